// Round 5
// baseline (4587.791 us; speedup 1.0000x reference)
//
#include <hip/hip_runtime.h>
#include <stdint.h>

// GDiffusionModel: encoder (D->NF->D) + 99x {3-layer gen + fused diffuse} + out.
// Noise = JAX threefry2x32 partitionable: bits[n] = w0^w1 of tf(key,(0,n)).
// 1024 thr/block, 32 lanes per row-pair; barrier-free main loop (all step
// data flow is intra-wave); a/s = per-lane multiplicative recurrence.

#define HALFB 8192
#define THREADS 1024
#define ZSTR 264          // z row stride (floats)
#define WS 36             // W3/W2/hbuf row stride

#define Z_OFF   0
#define W1_OFF  16896                 // [256][32] layer-1 weight
#define W3_OFF  (W1_OFF + 8192)      // [256][36] layer-3 weight transposed [d][g]
#define W2_OFF  (W3_OFF + 9216)      // [32][36]
#define HB_OFF  (W2_OFF + 1152)      // [64][36] h broadcast buffer
#define IA_OFF  (HB_OFF + 64*WS)     // [256] exp(+0.5*alpha/100)
#define IS_OFF  (IA_OFF + 256)       // [256] exp(-0.5*sigma/100)
#define B1_OFF  (IS_OFF + 256)       // [32]
#define B2_OFF  (B1_OFF + 32)        // [32]
#define B3_OFF  (B2_OFF + 32)        // [256]
#define LDS_FLOATS (B3_OFF + 256)    // 38592
#define LDS_BYTES  (LDS_FLOATS * 4)  // 154368 < 160 KiB

static_assert(LDS_BYTES <= 160*1024, "LDS overflow");

typedef float v2f __attribute__((ext_vector_type(2)));
typedef float v4f __attribute__((ext_vector_type(4)));

#define PKFMA(acc,s0,s1)   asm("v_pk_fma_f32 %0, %1, %2, %0" : "+v"(acc) : "v"(s0), "v"(s1))
#define PKFMA_L(acc,s0,s1) asm("v_pk_fma_f32 %0, %1, %2, %0 op_sel:[0,0,0] op_sel_hi:[0,1,1]" : "+v"(acc) : "v"(s0), "v"(s1))
#define PKFMA_H(acc,s0,s1) asm("v_pk_fma_f32 %0, %1, %2, %0 op_sel:[1,0,0] op_sel_hi:[1,1,1]" : "+v"(acc) : "v"(s0), "v"(s1))
#define PKMUL(d,a,b)       asm("v_pk_mul_f32 %0, %1, %2" : "=v"(d) : "v"(a), "v"(b))

__device__ __forceinline__ uint32_t rotl32(uint32_t v, int n) {
  return __builtin_amdgcn_alignbit(v, v, (uint32_t)(32 - n));
}

// Threefry-2x32, 20 rounds — matches jax/_src/prng.py exactly.
__device__ __forceinline__ void tf2x32(uint32_t k0, uint32_t k1,
                                       uint32_t& x0, uint32_t& x1) {
  uint32_t k2 = k0 ^ k1 ^ 0x1BD11BDAu;
  x0 += k0; x1 += k1;
#define TFR(r) { x0 += x1; x1 = rotl32(x1,(r)); x1 ^= x0; }
  TFR(13) TFR(15) TFR(26) TFR(6)
  x0 += k1; x1 += k2 + 1u;
  TFR(17) TFR(29) TFR(16) TFR(24)
  x0 += k2; x1 += k0 + 2u;
  TFR(13) TFR(15) TFR(26) TFR(6)
  x0 += k0; x1 += k1 + 3u;
  TFR(17) TFR(29) TFR(16) TFR(24)
  x0 += k1; x1 += k2 + 4u;
  TFR(13) TFR(15) TFR(26) TFR(6)
  x0 += k2; x1 += k0 + 5u;
#undef TFR
}

__device__ __forceinline__ uint32_t tf_bits(uint32_t k0, uint32_t k1, uint32_t n) {
  uint32_t x0 = 0u, x1 = n;
  tf2x32(k0, k1, x0, x1);
  return x0 ^ x1;
}

// two bit-draws -> two sqrt(2)*erfinv(uniform) normals; XLA ErfInv32 constants.
__device__ __forceinline__ v2f b2n_pk(uint32_t b0, uint32_t b1) {
  const float MN = -0.99999994039535522461f;   // nextafterf(-1,0)
  v2f f = { __uint_as_float((b0 >> 9) | 0x3F800000u),
            __uint_as_float((b1 >> 9) | 0x3F800000u) };
  v2f fm = f - 1.0f;                            // [0,1)
  v2f u = __builtin_elementwise_fma(fm, (v2f)2.0f, (v2f)MN);
  u = __builtin_elementwise_max(u, (v2f)MN);
  v2f x2 = u * u;
  v2f om = 1.0f - x2;
  v2f w  = { -__logf(om.x), -__logf(om.y) };
  v2f ws = w - 2.5f;
  v2f ps = (v2f)2.81022636e-08f;
  ps = __builtin_elementwise_fma(ps, ws, (v2f)3.43273939e-07f);
  ps = __builtin_elementwise_fma(ps, ws, (v2f)-3.5233877e-06f);
  ps = __builtin_elementwise_fma(ps, ws, (v2f)-4.39150654e-06f);
  ps = __builtin_elementwise_fma(ps, ws, (v2f)0.00021858087f);
  ps = __builtin_elementwise_fma(ps, ws, (v2f)-0.00125372503f);
  ps = __builtin_elementwise_fma(ps, ws, (v2f)-0.00417768164f);
  ps = __builtin_elementwise_fma(ps, ws, (v2f)0.246640727f);
  ps = __builtin_elementwise_fma(ps, ws, (v2f)1.50140941f);
  v2f p = ps;
  const int big = (w.x >= 5.0f) | (w.y >= 5.0f);
  if (__any(big)) {                       // rare tail (|u| > 0.9966)
    v2f sq = { sqrtf(w.x), sqrtf(w.y) };
    v2f wb = sq - 3.0f;
    v2f pb = (v2f)-0.000200214257f;
    pb = __builtin_elementwise_fma(pb, wb, (v2f)0.000100950558f);
    pb = __builtin_elementwise_fma(pb, wb, (v2f)0.00134934322f);
    pb = __builtin_elementwise_fma(pb, wb, (v2f)-0.00367342844f);
    pb = __builtin_elementwise_fma(pb, wb, (v2f)0.00573950773f);
    pb = __builtin_elementwise_fma(pb, wb, (v2f)-0.0076224613f);
    pb = __builtin_elementwise_fma(pb, wb, (v2f)0.00943887047f);
    pb = __builtin_elementwise_fma(pb, wb, (v2f)1.00167406f);
    pb = __builtin_elementwise_fma(pb, wb, (v2f)2.83297682f);
    p.x = (w.x < 5.0f) ? ps.x : pb.x;
    p.y = (w.y < 5.0f) ? ps.y : pb.y;
  }
  return (p * u) * 1.41421356237309515f;
}

__global__ __launch_bounds__(THREADS, 4)
void gdiff_kernel(const float* __restrict__ x,
                  const float* __restrict__ alpha, const float* __restrict__ sigma,
                  const float* __restrict__ ew1, const float* __restrict__ eb1,
                  const float* __restrict__ ew2, const float* __restrict__ eb2,
                  const float* __restrict__ gw1, const float* __restrict__ gb1,
                  const float* __restrict__ gw2, const float* __restrict__ gb2,
                  const float* __restrict__ gw3, const float* __restrict__ gb3,
                  float* __restrict__ out)
{
  extern __shared__ float sm[];
  const int t    = threadIdx.x;
  const int pr   = t >> 5;                  // row-pair 0..31
  const int c    = t & 31;
  const int half = c >> 4;                  // which row of the pair
  const int cf   = c & 15;                  // lane-in-row 0..15
  const int q    = cf & 7;                  // f/g quad index
  const int dh   = cf >> 3;                 // d-half / f-half for L1/L2 split
  const int rid  = pr + (half << 5);        // LDS row 0..63
  const int zrow = rid * ZSTR + (half << 3);// +8 float shift decorrelates halves
  const uint32_t rowg = (uint32_t)(blockIdx.x * 32 + pr + half * HALFB);
  const uint32_t nb   = rowg * 256u + (uint32_t)cf;

  v4f hq0, hq1, hq2, hq3, hq4, hq5, hq6, hq7;  // 32 broadcast h values
  v2f av[8], sv[8];                            // a(d), s(d) at this lane's 16 d's

  // ---------- staging helpers ----------
  auto stage_w1 = [&](const float* __restrict__ w) {   // [256][32]
    const int r = t >> 2, part = t & 3;
#pragma unroll
    for (int s = 0; s < 2; ++s)
      *(v4f*)&sm[W1_OFF + r * 32 + part * 8 + 4 * s] =
          *(const v4f*)&w[r * 32 + part * 8 + 4 * s];
  };
  auto stage_w3t = [&](const float* __restrict__ w) {  // [32][256] -> [d][g]
    const int g = t >> 5, dc = t & 31;
#pragma unroll
    for (int s = 0; s < 2; ++s) {
      const int d0 = dc * 8 + s * 4;
      v4f v = *(const v4f*)&w[g * 256 + d0];
      sm[W3_OFF + (d0 + 0) * WS + g] = v.x;
      sm[W3_OFF + (d0 + 1) * WS + g] = v.y;
      sm[W3_OFF + (d0 + 2) * WS + g] = v.z;
      sm[W3_OFF + (d0 + 3) * WS + g] = v.w;
    }
  };

  // ---------- layer 1: d-half-split partials ----------
  auto layer1 = [&](v2f& h01, v2f& h23) {
    v4f bv = { 0.f, 0.f, 0.f, 0.f };
    if (!dh) bv = *(const v4f*)&sm[B1_OFF + 4 * q];
    h01 = bv.xy; h23 = bv.zw;
    const float* zr_ = &sm[zrow + (dh << 7)];
    const float* wp  = &sm[W1_OFF + (dh << 12) + 4 * q];
#pragma unroll 4
    for (int d0 = 0; d0 < 128; d0 += 4) {
      v4f z4 = *(const v4f*)&zr_[d0];
      v4f wa = *(const v4f*)&wp[(d0 + 0) * 32];
      v4f wb = *(const v4f*)&wp[(d0 + 1) * 32];
      v4f wc = *(const v4f*)&wp[(d0 + 2) * 32];
      v4f wd = *(const v4f*)&wp[(d0 + 3) * 32];
      PKFMA_L(h01, z4.xy, wa.xy); PKFMA_L(h23, z4.xy, wa.zw);
      PKFMA_H(h01, z4.xy, wb.xy); PKFMA_H(h23, z4.xy, wb.zw);
      PKFMA_L(h01, z4.zw, wc.xy); PKFMA_L(h23, z4.zw, wc.zw);
      PKFMA_H(h01, z4.zw, wd.xy); PKFMA_H(h23, z4.zw, wd.zw);
    }
  };
  auto red8_relu = [&](v2f& a, v2f& b) {     // cross-half reduce + relu
    a.x += __shfl_xor(a.x, 8); a.y += __shfl_xor(a.y, 8);
    b.x += __shfl_xor(b.x, 8); b.y += __shfl_xor(b.y, 8);
    a = __builtin_elementwise_max(a, (v2f)0.f);
    b = __builtin_elementwise_max(b, (v2f)0.f);
  };
  auto hwrite = [&](v2f a, v2f b) {
    if (!dh) { v4f hv; hv.xy = a; hv.zw = b;
               *(v4f*)&sm[HB_OFF + rid * WS + 4 * q] = hv; }
  };
  auto hload8 = [&]() {
    const float* hb = &sm[HB_OFF + rid * WS];
    hq0 = *(const v4f*)&hb[0];  hq1 = *(const v4f*)&hb[4];
    hq2 = *(const v4f*)&hb[8];  hq3 = *(const v4f*)&hb[12];
    hq4 = *(const v4f*)&hb[16]; hq5 = *(const v4f*)&hb[20];
    hq6 = *(const v4f*)&hb[24]; hq7 = *(const v4f*)&hb[28];
  };
  // ---------- layer 2: f-half-split partials ----------
  auto layer2 = [&](v2f& g01, v2f& g23) {
    const float* hb = &sm[HB_OFF + rid * WS + (dh << 4)];
    v4f hA = *(const v4f*)&hb[0], hB = *(const v4f*)&hb[4];
    v4f hC = *(const v4f*)&hb[8], hD = *(const v4f*)&hb[12];
    v4f bv = { 0.f, 0.f, 0.f, 0.f };
    if (!dh) bv = *(const v4f*)&sm[B2_OFF + 4 * q];
    g01 = bv.xy; g23 = bv.zw;
    const float* w2c = &sm[W2_OFF + (dh << 4) * WS + 4 * q];
#define L2M(hqm, mm) { \
    v4f wA = *(const v4f*)&w2c[(4*(mm)+0)*WS]; \
    v4f wB = *(const v4f*)&w2c[(4*(mm)+1)*WS]; \
    v4f wC = *(const v4f*)&w2c[(4*(mm)+2)*WS]; \
    v4f wD = *(const v4f*)&w2c[(4*(mm)+3)*WS]; \
    PKFMA_L(g01, hqm.xy, wA.xy); PKFMA_L(g23, hqm.xy, wA.zw); \
    PKFMA_H(g01, hqm.xy, wB.xy); PKFMA_H(g23, hqm.xy, wB.zw); \
    PKFMA_L(g01, hqm.zw, wC.xy); PKFMA_L(g23, hqm.zw, wC.zw); \
    PKFMA_H(g01, hqm.zw, wD.xy); PKFMA_H(g23, hqm.zw, wD.zw); }
    L2M(hA,0) L2M(hB,1) L2M(hC,2) L2M(hD,3)
#undef L2M
  };
  // ---------- layer 3 (or encoder L2) + fused diffuse; z -> LDS ----------
  auto l3d = [&](uint32_t e0, uint32_t e1, bool relu) {
#pragma unroll
    for (int kp = 0; kp < 8; ++kp) {
      const int dlo = cf + 32 * kp;
      const int dhi = dlo + 16;
      v2f acc0 = { sm[B3_OFF + dlo], 0.f };
      v2f acc1 = { sm[B3_OFF + dhi], 0.f };
      const float* wl = &sm[W3_OFF + dlo * WS];
      const float* wh = &sm[W3_OFF + dhi * WS];
#define L3M(hqm, off) { \
      v4f wvl = *(const v4f*)&wl[off]; \
      v4f wvh = *(const v4f*)&wh[off]; \
      PKFMA(acc0, hqm.xy, wvl.xy); PKFMA(acc0, hqm.zw, wvl.zw); \
      PKFMA(acc1, hqm.xy, wvh.xy); PKFMA(acc1, hqm.zw, wvh.zw); }
      L3M(hq0, 0)  L3M(hq1, 4)  L3M(hq2, 8)  L3M(hq3, 12)
      L3M(hq4, 16) L3M(hq5, 20) L3M(hq6, 24) L3M(hq7, 28)
#undef L3M
      float z0 = acc0.x + acc0.y;
      float z1 = acc1.x + acc1.y;
      if (relu) { z0 = fmaxf(z0, 0.f); z1 = fmaxf(z1, 0.f); }
      const uint32_t n0 = nb + (uint32_t)(32 * kp);
      v2f nrm = b2n_pk(tf_bits(e0, e1, n0), tf_bits(e0, e1, n0 + 16u));
      v2f z2 = { z0, z1 };
      v2f zd; PKMUL(zd, z2, av[kp]); PKFMA(zd, sv[kp], nrm);
      sm[zrow + dlo] = zd.x;
      sm[zrow + dhi] = zd.y;
    }
  };

  // ---------------- stage x + encoder weights + tables ----------------
  {
    const int zr = t >> 4, jj = t & 15;
    const int gr = (zr < 32) ? (blockIdx.x * 32 + zr)
                             : (blockIdx.x * 32 + zr - 32 + HALFB);
    const v4f* src = (const v4f*)(x + (size_t)gr * 256 + jj * 16);
    const int zb = zr * ZSTR + ((zr >> 5) << 3);
#pragma unroll
    for (int s = 0; s < 4; ++s)
      *(v4f*)&sm[zb + jj * 16 + 4 * s] = src[s];
  }
  stage_w1(ew1);
  stage_w3t(ew2);
  if (t < 256)      sm[IA_OFF + t]         = __expf( 0.5f * alpha[t] * 0.01f);
  else if (t < 512) sm[IS_OFF + (t - 256)] = __expf(-0.5f * sigma[t - 256] * 0.01f);
  if (t < 256) sm[B3_OFF + t] = eb2[t];
  if (t < 32)  sm[B1_OFF + t] = eb1[t];
  // per-lane a/s state at j=99
#pragma unroll
  for (int kp = 0; kp < 8; ++kp) {
    const int dlo = cf + 32 * kp, dhi = dlo + 16;
    av[kp] = v2f{ __expf(-0.5f * alpha[dlo] * 0.99f), __expf(-0.5f * alpha[dhi] * 0.99f) };
    sv[kp] = v2f{ __expf( 0.5f * sigma[dlo] * 0.99f), __expf( 0.5f * sigma[dhi] * 0.99f) };
  }
  __syncthreads();

  // ---------------- encoder: L1(+relu) -> L2(no relu) + diffuse(99) ----------------
  {
    v2f h01, h23;
    layer1(h01, h23);
    red8_relu(h01, h23);
    hwrite(h01, h23);
    hload8();
    uint32_t e0 = 0u, e1 = 99u;
    tf2x32(0u, 42u, e0, e1);
    l3d(e0, e1, false);
  }
  __syncthreads();

  // ---------------- restage generator weights ----------------
  stage_w1(gw1);
  stage_w3t(gw3);
  if (t < 256) {
    sm[B3_OFF + t] = gb3[t];
    if (t < 32) { sm[B1_OFF + t] = gb1[t]; sm[B2_OFF + t] = gb2[t]; }
    const int r = t >> 3, s8 = t & 7;   // gw2 [32][32] -> [32][36]
    *(v4f*)&sm[W2_OFF + r * WS + 4 * s8] = *(const v4f*)&gw2[r * 32 + 4 * s8];
  }
  __syncthreads();

  // ---------------- 99 iterations, BARRIER-FREE ----------------
#pragma unroll 1
  for (int i = 99; i >= 1; --i) {
    const int j = i - 1;
    // a/s recurrence: j_prev -> j
#pragma unroll
    for (int kp = 0; kp < 8; ++kp) {
      const int dlo = cf + 32 * kp, dhi = dlo + 16;
      v2f ia  = { sm[IA_OFF + dlo], sm[IA_OFF + dhi] };
      v2f is_ = { sm[IS_OFF + dlo], sm[IS_OFF + dhi] };
      PKMUL(av[kp], av[kp], ia);
      PKMUL(sv[kp], sv[kp], is_);
    }
    v2f h01, h23;
    layer1(h01, h23);
    red8_relu(h01, h23);
    hwrite(h01, h23);

    v2f g01, g23;
    layer2(g01, g23);
    red8_relu(g01, g23);
    hwrite(g01, g23);
    hload8();

    uint32_t e0 = 0u, e1 = (uint32_t)j;
    tf2x32(0u, 42u, e0, e1);
    l3d(e0, e1, true);
  }
  __syncthreads();

  // ---------------- coalesced output copy ----------------
  {
    const int zr = t >> 4, jj = t & 15;
    const int gr = (zr < 32) ? (blockIdx.x * 32 + zr)
                             : (blockIdx.x * 32 + zr - 32 + HALFB);
    v4f* dst = (v4f*)(out + (size_t)gr * 256 + jj * 16);
    const int zb = zr * ZSTR + ((zr >> 5) << 3);
#pragma unroll
    for (int s = 0; s < 4; ++s)
      dst[s] = *(const v4f*)&sm[zb + jj * 16 + 4 * s];
  }
}

extern "C" void kernel_launch(void* const* d_in, const int* in_sizes, int n_in,
                              void* d_out, int out_size, void* d_ws, size_t ws_size,
                              hipStream_t stream) {
  (void)in_sizes; (void)n_in; (void)d_ws; (void)ws_size; (void)out_size;
  const float* x     = (const float*)d_in[0];
  const float* alpha = (const float*)d_in[1];
  const float* sigma = (const float*)d_in[2];
  const float* ew1   = (const float*)d_in[3];
  const float* eb1   = (const float*)d_in[4];
  const float* ew2   = (const float*)d_in[5];
  const float* eb2   = (const float*)d_in[6];
  const float* gw1   = (const float*)d_in[7];
  const float* gb1   = (const float*)d_in[8];
  const float* gw2   = (const float*)d_in[9];
  const float* gb2   = (const float*)d_in[10];
  const float* gw3   = (const float*)d_in[11];
  const float* gb3   = (const float*)d_in[12];
  float* out = (float*)d_out;

  (void)hipFuncSetAttribute((const void*)gdiff_kernel,
                            hipFuncAttributeMaxDynamicSharedMemorySize, LDS_BYTES);

  gdiff_kernel<<<256, THREADS, LDS_BYTES, stream>>>(
      x, alpha, sigma, ew1, eb1, ew2, eb2, gw1, gb1, gw2, gb2, gw3, gb3, out);
}

// Round 8
// 4403.183 us; speedup vs baseline: 1.0419x; 1.0419x over previous
//
#include <hip/hip_runtime.h>
#include <stdint.h>

// GDiffusionModel: encoder (D->NF->D) + 99x {3-layer gen + fused diffuse} + out.
// Noise = JAX threefry2x32 partitionable: bits[n] = w0^w1 of tf(key,(0,n)).
// 1024 thr/block (16 waves/CU, 4/SIMD); 32 lanes per row-pair; one barrier per
// step for the double-buffered a/s exp table; NO per-thread arrays (no spills).

#define HALFB 8192
#define THREADS 1024
#define ZSTR 264          // z row stride (floats)
#define WS 36             // W3/W2/hbuf row stride

#define Z_OFF   0                    // [64][264] z rows (16896)
#define W1_OFF  16896                // [256][32] layer-1 weight (8192)
#define W3_OFF  (W1_OFF + 8192)      // [256][36] layer-3 weight transposed (9216)
#define W2_OFF  (W3_OFF + 9216)      // [32][36] (1152)
#define HB_OFF  (W2_OFF + 1152)      // [64][36] h broadcast buffer (2304)
#define AE_OFF  (HB_OFF + 2304)      // [2][256] a=exp(-.5*alpha*t) dbuf (512)
#define SE_OFF  (AE_OFF + 512)       // [2][256] s=exp(+.5*sigma*t) dbuf (512)
#define AL_OFF  (SE_OFF + 512)       // [256] alpha
#define SG_OFF  (AL_OFF + 256)       // [256] sigma
#define B1_OFF  (SG_OFF + 256)       // [32]
#define B2_OFF  (B1_OFF + 32)        // [32]
#define B3_OFF  (B2_OFF + 32)        // [256]
#define LDS_FLOATS (B3_OFF + 256)    // 39616
#define LDS_BYTES  (LDS_FLOATS * 4)  // 158464 < 160 KiB

static_assert(LDS_BYTES <= 160*1024, "LDS overflow");

typedef float v2f __attribute__((ext_vector_type(2)));
typedef float v4f __attribute__((ext_vector_type(4)));

#define PKFMA(acc,s0,s1)   asm("v_pk_fma_f32 %0, %1, %2, %0" : "+v"(acc) : "v"(s0), "v"(s1))
#define PKFMA_L(acc,s0,s1) asm("v_pk_fma_f32 %0, %1, %2, %0 op_sel:[0,0,0] op_sel_hi:[0,1,1]" : "+v"(acc) : "v"(s0), "v"(s1))
#define PKFMA_H(acc,s0,s1) asm("v_pk_fma_f32 %0, %1, %2, %0 op_sel:[1,0,0] op_sel_hi:[1,1,1]" : "+v"(acc) : "v"(s0), "v"(s1))
#define PKMUL(d,a,b)       asm("v_pk_mul_f32 %0, %1, %2" : "=v"(d) : "v"(a), "v"(b))

__device__ __forceinline__ uint32_t rotl32(uint32_t v, int n) {
  return __builtin_amdgcn_alignbit(v, v, (uint32_t)(32 - n));
}

// Threefry-2x32, 20 rounds — matches jax/_src/prng.py exactly.
__device__ __forceinline__ void tf2x32(uint32_t k0, uint32_t k1,
                                       uint32_t& x0, uint32_t& x1) {
  uint32_t k2 = k0 ^ k1 ^ 0x1BD11BDAu;
  x0 += k0; x1 += k1;
#define TFR(r) { x0 += x1; x1 = rotl32(x1,(r)); x1 ^= x0; }
  TFR(13) TFR(15) TFR(26) TFR(6)
  x0 += k1; x1 += k2 + 1u;
  TFR(17) TFR(29) TFR(16) TFR(24)
  x0 += k2; x1 += k0 + 2u;
  TFR(13) TFR(15) TFR(26) TFR(6)
  x0 += k0; x1 += k1 + 3u;
  TFR(17) TFR(29) TFR(16) TFR(24)
  x0 += k1; x1 += k2 + 4u;
  TFR(13) TFR(15) TFR(26) TFR(6)
  x0 += k2; x1 += k0 + 5u;
#undef TFR
}

__device__ __forceinline__ uint32_t tf_bits(uint32_t k0, uint32_t k1, uint32_t n) {
  uint32_t x0 = 0u, x1 = n;
  tf2x32(k0, k1, x0, x1);
  return x0 ^ x1;
}

// two bit-draws -> two sqrt(2)*erfinv(uniform) normals; XLA ErfInv32 constants.
__device__ __forceinline__ v2f b2n_pk(uint32_t b0, uint32_t b1) {
  const float MN = -0.99999994039535522461f;   // nextafterf(-1,0)
  v2f f = { __uint_as_float((b0 >> 9) | 0x3F800000u),
            __uint_as_float((b1 >> 9) | 0x3F800000u) };
  v2f fm = f - 1.0f;                            // [0,1)
  v2f u = __builtin_elementwise_fma(fm, (v2f)2.0f, (v2f)MN);
  u = __builtin_elementwise_max(u, (v2f)MN);
  v2f x2 = u * u;
  v2f om = 1.0f - x2;
  v2f w  = { -__logf(om.x), -__logf(om.y) };
  v2f ws = w - 2.5f;
  v2f ps = (v2f)2.81022636e-08f;
  ps = __builtin_elementwise_fma(ps, ws, (v2f)3.43273939e-07f);
  ps = __builtin_elementwise_fma(ps, ws, (v2f)-3.5233877e-06f);
  ps = __builtin_elementwise_fma(ps, ws, (v2f)-4.39150654e-06f);
  ps = __builtin_elementwise_fma(ps, ws, (v2f)0.00021858087f);
  ps = __builtin_elementwise_fma(ps, ws, (v2f)-0.00125372503f);
  ps = __builtin_elementwise_fma(ps, ws, (v2f)-0.00417768164f);
  ps = __builtin_elementwise_fma(ps, ws, (v2f)0.246640727f);
  ps = __builtin_elementwise_fma(ps, ws, (v2f)1.50140941f);
  v2f p = ps;
  const int big = (w.x >= 5.0f) | (w.y >= 5.0f);
  if (__any(big)) {                       // rare tail (|u| > 0.9966)
    v2f sq = { sqrtf(w.x), sqrtf(w.y) };
    v2f wb = sq - 3.0f;
    v2f pb = (v2f)-0.000200214257f;
    pb = __builtin_elementwise_fma(pb, wb, (v2f)0.000100950558f);
    pb = __builtin_elementwise_fma(pb, wb, (v2f)0.00134934322f);
    pb = __builtin_elementwise_fma(pb, wb, (v2f)-0.00367342844f);
    pb = __builtin_elementwise_fma(pb, wb, (v2f)0.00573950773f);
    pb = __builtin_elementwise_fma(pb, wb, (v2f)-0.0076224613f);
    pb = __builtin_elementwise_fma(pb, wb, (v2f)0.00943887047f);
    pb = __builtin_elementwise_fma(pb, wb, (v2f)1.00167406f);
    pb = __builtin_elementwise_fma(pb, wb, (v2f)2.83297682f);
    p.x = (w.x < 5.0f) ? ps.x : pb.x;
    p.y = (w.y < 5.0f) ? ps.y : pb.y;
  }
  return (p * u) * 1.41421356237309515f;
}

__global__ __launch_bounds__(THREADS, 4)
void gdiff_kernel(const float* __restrict__ x,
                  const float* __restrict__ alpha, const float* __restrict__ sigma,
                  const float* __restrict__ ew1, const float* __restrict__ eb1,
                  const float* __restrict__ ew2, const float* __restrict__ eb2,
                  const float* __restrict__ gw1, const float* __restrict__ gb1,
                  const float* __restrict__ gw2, const float* __restrict__ gb2,
                  const float* __restrict__ gw3, const float* __restrict__ gb3,
                  float* __restrict__ out)
{
  extern __shared__ float sm[];
  const int t    = threadIdx.x;
  const int pr   = t >> 5;                  // row-pair 0..31
  const int c    = t & 31;
  const int half = c >> 4;                  // which row of the pair
  const int cf   = c & 15;                  // lane-in-row 0..15
  const int q    = cf & 7;                  // f/g quad index
  const int dh   = cf >> 3;                 // d-half / f-half for L1/L2 split
  const int rid  = pr + (half << 5);        // LDS row 0..63
  const int zrow = rid * ZSTR + (half << 3);// +8 float shift decorrelates halves
  const uint32_t rowg = (uint32_t)(blockIdx.x * 32 + pr + half * HALFB);
  const uint32_t nb   = rowg * 256u + (uint32_t)cf;

  v4f hq0, hq1, hq2, hq3, hq4, hq5, hq6, hq7;  // 32 broadcast h values

  // ---------- staging helpers ----------
  auto stage_w1 = [&](const float* __restrict__ w) {   // [256][32]
    const int r = t >> 2, part = t & 3;
#pragma unroll
    for (int s = 0; s < 2; ++s)
      *(v4f*)&sm[W1_OFF + r * 32 + part * 8 + 4 * s] =
          *(const v4f*)&w[r * 32 + part * 8 + 4 * s];
  };
  auto stage_w3t = [&](const float* __restrict__ w) {  // [32][256] -> [d][g]
    const int g = t >> 5, dc = t & 31;
#pragma unroll
    for (int s = 0; s < 2; ++s) {
      const int d0 = dc * 8 + s * 4;
      v4f v = *(const v4f*)&w[g * 256 + d0];
      sm[W3_OFF + (d0 + 0) * WS + g] = v.x;
      sm[W3_OFF + (d0 + 1) * WS + g] = v.y;
      sm[W3_OFF + (d0 + 2) * WS + g] = v.z;
      sm[W3_OFF + (d0 + 3) * WS + g] = v.w;
    }
  };

  // ---------- layer 1: d-half-split partials ----------
  auto layer1 = [&](v2f& h01, v2f& h23) {
    v4f bv = { 0.f, 0.f, 0.f, 0.f };
    if (!dh) bv = *(const v4f*)&sm[B1_OFF + 4 * q];
    h01 = bv.xy; h23 = bv.zw;
    const float* zr_ = &sm[zrow + (dh << 7)];
    const float* wp  = &sm[W1_OFF + (dh << 12) + 4 * q];
#pragma unroll 4
    for (int d0 = 0; d0 < 128; d0 += 4) {
      v4f z4 = *(const v4f*)&zr_[d0];
      v4f wa = *(const v4f*)&wp[(d0 + 0) * 32];
      v4f wb = *(const v4f*)&wp[(d0 + 1) * 32];
      v4f wc = *(const v4f*)&wp[(d0 + 2) * 32];
      v4f wd = *(const v4f*)&wp[(d0 + 3) * 32];
      PKFMA_L(h01, z4.xy, wa.xy); PKFMA_L(h23, z4.xy, wa.zw);
      PKFMA_H(h01, z4.xy, wb.xy); PKFMA_H(h23, z4.xy, wb.zw);
      PKFMA_L(h01, z4.zw, wc.xy); PKFMA_L(h23, z4.zw, wc.zw);
      PKFMA_H(h01, z4.zw, wd.xy); PKFMA_H(h23, z4.zw, wd.zw);
    }
  };
  auto red8_relu = [&](v2f& a, v2f& b) {     // cross-half reduce + relu
    a.x += __shfl_xor(a.x, 8); a.y += __shfl_xor(a.y, 8);
    b.x += __shfl_xor(b.x, 8); b.y += __shfl_xor(b.y, 8);
    a = __builtin_elementwise_max(a, (v2f)0.f);
    b = __builtin_elementwise_max(b, (v2f)0.f);
  };
  auto hwrite = [&](v2f a, v2f b) {
    if (!dh) { v4f hv; hv.xy = a; hv.zw = b;
               *(v4f*)&sm[HB_OFF + rid * WS + 4 * q] = hv; }
  };
  auto hload8 = [&]() {
    const float* hb = &sm[HB_OFF + rid * WS];
    hq0 = *(const v4f*)&hb[0];  hq1 = *(const v4f*)&hb[4];
    hq2 = *(const v4f*)&hb[8];  hq3 = *(const v4f*)&hb[12];
    hq4 = *(const v4f*)&hb[16]; hq5 = *(const v4f*)&hb[20];
    hq6 = *(const v4f*)&hb[24]; hq7 = *(const v4f*)&hb[28];
  };
  // ---------- layer 2: f-half-split partials ----------
  auto layer2 = [&](v2f& g01, v2f& g23) {
    const float* hb = &sm[HB_OFF + rid * WS + (dh << 4)];
    v4f hA = *(const v4f*)&hb[0], hB = *(const v4f*)&hb[4];
    v4f hC = *(const v4f*)&hb[8], hD = *(const v4f*)&hb[12];
    v4f bv = { 0.f, 0.f, 0.f, 0.f };
    if (!dh) bv = *(const v4f*)&sm[B2_OFF + 4 * q];
    g01 = bv.xy; g23 = bv.zw;
    const float* w2c = &sm[W2_OFF + (dh << 4) * WS + 4 * q];
#define L2M(hqm, mm) { \
    v4f wA = *(const v4f*)&w2c[(4*(mm)+0)*WS]; \
    v4f wB = *(const v4f*)&w2c[(4*(mm)+1)*WS]; \
    v4f wC = *(const v4f*)&w2c[(4*(mm)+2)*WS]; \
    v4f wD = *(const v4f*)&w2c[(4*(mm)+3)*WS]; \
    PKFMA_L(g01, hqm.xy, wA.xy); PKFMA_L(g23, hqm.xy, wA.zw); \
    PKFMA_H(g01, hqm.xy, wB.xy); PKFMA_H(g23, hqm.xy, wB.zw); \
    PKFMA_L(g01, hqm.zw, wC.xy); PKFMA_L(g23, hqm.zw, wC.zw); \
    PKFMA_H(g01, hqm.zw, wD.xy); PKFMA_H(g23, hqm.zw, wD.zw); }
    L2M(hA,0) L2M(hB,1) L2M(hC,2) L2M(hD,3)
#undef L2M
  };
  // ---------- layer 3 (or encoder L2) + fused diffuse; z -> LDS ----------
  auto l3d = [&](uint32_t e0, uint32_t e1, const float* ae, const float* se,
                 bool relu) {
#pragma unroll
    for (int kp = 0; kp < 8; ++kp) {
      const int dlo = cf + 32 * kp;
      const int dhi = dlo + 16;
      v2f acc0 = { sm[B3_OFF + dlo], 0.f };
      v2f acc1 = { sm[B3_OFF + dhi], 0.f };
      const float* wl = &sm[W3_OFF + dlo * WS];
      const float* wh = &sm[W3_OFF + dhi * WS];
#define L3M(hqm, off) { \
      v4f wvl = *(const v4f*)&wl[off]; \
      v4f wvh = *(const v4f*)&wh[off]; \
      PKFMA(acc0, hqm.xy, wvl.xy); PKFMA(acc0, hqm.zw, wvl.zw); \
      PKFMA(acc1, hqm.xy, wvh.xy); PKFMA(acc1, hqm.zw, wvh.zw); }
      L3M(hq0, 0)  L3M(hq1, 4)  L3M(hq2, 8)  L3M(hq3, 12)
      L3M(hq4, 16) L3M(hq5, 20) L3M(hq6, 24) L3M(hq7, 28)
#undef L3M
      float z0 = acc0.x + acc0.y;
      float z1 = acc1.x + acc1.y;
      if (relu) { z0 = fmaxf(z0, 0.f); z1 = fmaxf(z1, 0.f); }
      const uint32_t n0 = nb + (uint32_t)(32 * kp);
      v2f nrm = b2n_pk(tf_bits(e0, e1, n0), tf_bits(e0, e1, n0 + 16u));
      v2f a2 = { ae[dlo], ae[dhi] };
      v2f s2 = { se[dlo], se[dhi] };
      v2f z2 = { z0, z1 };
      v2f zd; PKMUL(zd, z2, a2); PKFMA(zd, s2, nrm);
      sm[zrow + dlo] = zd.x;
      sm[zrow + dhi] = zd.y;
    }
  };

  // ---------------- stage x + encoder weights + tables ----------------
  {
    const int zr = t >> 4, jj = t & 15;
    const int gr = (zr < 32) ? (blockIdx.x * 32 + zr)
                             : (blockIdx.x * 32 + zr - 32 + HALFB);
    const v4f* src = (const v4f*)(x + (size_t)gr * 256 + jj * 16);
    const int zb = zr * ZSTR + ((zr >> 5) << 3);
#pragma unroll
    for (int s = 0; s < 4; ++s)
      *(v4f*)&sm[zb + jj * 16 + 4 * s] = src[s];
  }
  stage_w1(ew1);
  stage_w3t(ew2);
  if (t < 256) {
    const float al = alpha[t];
    sm[AL_OFF + t] = al;
    sm[AE_OFF + 256 + t] = __expf(-0.5f * al * 0.99f);   // a-table for j=99 (buf 1)
    sm[B3_OFF + t] = eb2[t];
    if (t < 32) sm[B1_OFF + t] = eb1[t];
  } else if (t < 512) {
    const int d = t - 256;
    const float sg = sigma[d];
    sm[SG_OFF + d] = sg;
    sm[SE_OFF + 256 + d] = __expf(0.5f * sg * 0.99f);    // s-table for j=99 (buf 1)
  }
  __syncthreads();

  // ---------------- encoder: L1(+relu) -> L2(no relu) + diffuse(99) ----------------
  {
    v2f h01, h23;
    layer1(h01, h23);
    red8_relu(h01, h23);
    hwrite(h01, h23);
    hload8();
    uint32_t e0 = 0u, e1 = 99u;
    tf2x32(0u, 42u, e0, e1);
    l3d(e0, e1, &sm[AE_OFF + 256], &sm[SE_OFF + 256], false);
  }
  __syncthreads();

  // ---------------- restage generator weights ----------------
  stage_w1(gw1);
  stage_w3t(gw3);
  if (t < 256) {
    sm[B3_OFF + t] = gb3[t];
    if (t < 32) { sm[B1_OFF + t] = gb1[t]; sm[B2_OFF + t] = gb2[t]; }
    const int r = t >> 3, s8 = t & 7;   // gw2 [32][32] -> [32][36]
    *(v4f*)&sm[W2_OFF + r * WS + 4 * s8] = *(const v4f*)&gw2[r * 32 + 4 * s8];
  }
  __syncthreads();

  // ---------------- 99 iterations: 1 barrier/step (a/s table dbuf) ----------------
#pragma unroll 1
  for (int i = 99; i >= 1; --i) {
    const int j = i - 1;
    const float tt = (float)j * 0.01f;
    const int buf = (j & 1) << 8;
    if (t < 256)      sm[AE_OFF + buf + t]       = __expf(-0.5f * sm[AL_OFF + t] * tt);
    else if (t < 512) sm[SE_OFF + buf + (t-256)] = __expf( 0.5f * sm[SG_OFF + (t-256)] * tt);
    __syncthreads();   // table(j) ready; also fences z hand-off parity

    v2f h01, h23;
    layer1(h01, h23);
    red8_relu(h01, h23);
    hwrite(h01, h23);

    v2f g01, g23;
    layer2(g01, g23);
    red8_relu(g01, g23);
    hwrite(g01, g23);
    hload8();

    uint32_t e0 = 0u, e1 = (uint32_t)j;
    tf2x32(0u, 42u, e0, e1);
    l3d(e0, e1, &sm[AE_OFF + buf], &sm[SE_OFF + buf], true);
  }
  __syncthreads();

  // ---------------- coalesced output copy ----------------
  {
    const int zr = t >> 4, jj = t & 15;
    const int gr = (zr < 32) ? (blockIdx.x * 32 + zr)
                             : (blockIdx.x * 32 + zr - 32 + HALFB);
    v4f* dst = (v4f*)(out + (size_t)gr * 256 + jj * 16);
    const int zb = zr * ZSTR + ((zr >> 5) << 3);
#pragma unroll
    for (int s = 0; s < 4; ++s)
      dst[s] = *(const v4f*)&sm[zb + jj * 16 + 4 * s];
  }
}

extern "C" void kernel_launch(void* const* d_in, const int* in_sizes, int n_in,
                              void* d_out, int out_size, void* d_ws, size_t ws_size,
                              hipStream_t stream) {
  (void)in_sizes; (void)n_in; (void)d_ws; (void)ws_size; (void)out_size;
  const float* x     = (const float*)d_in[0];
  const float* alpha = (const float*)d_in[1];
  const float* sigma = (const float*)d_in[2];
  const float* ew1   = (const float*)d_in[3];
  const float* eb1   = (const float*)d_in[4];
  const float* ew2   = (const float*)d_in[5];
  const float* eb2   = (const float*)d_in[6];
  const float* gw1   = (const float*)d_in[7];
  const float* gb1   = (const float*)d_in[8];
  const float* gw2   = (const float*)d_in[9];
  const float* gb2   = (const float*)d_in[10];
  const float* gw3   = (const float*)d_in[11];
  const float* gb3   = (const float*)d_in[12];
  float* out = (float*)d_out;

  (void)hipFuncSetAttribute((const void*)gdiff_kernel,
                            hipFuncAttributeMaxDynamicSharedMemorySize, LDS_BYTES);

  gdiff_kernel<<<256, THREADS, LDS_BYTES, stream>>>(
      x, alpha, sigma, ew1, eb1, ew2, eb2, gw1, gb1, gw2, gb2, gw3, gb3, out);
}

// Round 9
// 4397.813 us; speedup vs baseline: 1.0432x; 1.0012x over previous
//
#include <hip/hip_runtime.h>
#include <stdint.h>

// GDiffusionModel: encoder (D->NF->D) + 99x {3-layer gen + fused diffuse} + out.
// Noise = JAX threefry2x32 partitionable: bits[n] = w0^w1 of tf(key,(0,n)).
// 1024 thr/block (16 waves/CU, 4/SIMD); 32 lanes per row-pair; one barrier per
// step for the double-buffered a/s exp table; NO per-thread arrays.
// __launch_bounds__(1024) ONLY — second arg triggered a 64-VGPR spill config
// (r5/r8: FETCH 6-8 GB scratch traffic); bare form derives the 128-reg cap
// from flat-workgroup-size feasibility.

#define HALFB 8192
#define THREADS 1024
#define ZSTR 264          // z row stride (floats)
#define WS 36             // W3/W2/hbuf row stride

#define Z_OFF   0                    // [64][264] z rows (16896)
#define W1_OFF  16896                // [256][32] layer-1 weight (8192)
#define W3_OFF  (W1_OFF + 8192)      // [256][36] layer-3 weight transposed (9216)
#define W2_OFF  (W3_OFF + 9216)      // [32][36] (1152)
#define HB_OFF  (W2_OFF + 1152)      // [64][36] h broadcast buffer (2304)
#define AE_OFF  (HB_OFF + 2304)      // [2][256] a=exp(-.5*alpha*t) dbuf (512)
#define SE_OFF  (AE_OFF + 512)       // [2][256] s=exp(+.5*sigma*t) dbuf (512)
#define AL_OFF  (SE_OFF + 512)       // [256] alpha
#define SG_OFF  (AL_OFF + 256)       // [256] sigma
#define B1_OFF  (SG_OFF + 256)       // [32]
#define B2_OFF  (B1_OFF + 32)        // [32]
#define B3_OFF  (B2_OFF + 32)        // [256]
#define LDS_FLOATS (B3_OFF + 256)    // 39616
#define LDS_BYTES  (LDS_FLOATS * 4)  // 158464 < 160 KiB

static_assert(LDS_BYTES <= 160*1024, "LDS overflow");

typedef float v2f __attribute__((ext_vector_type(2)));
typedef float v4f __attribute__((ext_vector_type(4)));

#define PKFMA(acc,s0,s1)   asm("v_pk_fma_f32 %0, %1, %2, %0" : "+v"(acc) : "v"(s0), "v"(s1))
#define PKFMA_L(acc,s0,s1) asm("v_pk_fma_f32 %0, %1, %2, %0 op_sel:[0,0,0] op_sel_hi:[0,1,1]" : "+v"(acc) : "v"(s0), "v"(s1))
#define PKFMA_H(acc,s0,s1) asm("v_pk_fma_f32 %0, %1, %2, %0 op_sel:[1,0,0] op_sel_hi:[1,1,1]" : "+v"(acc) : "v"(s0), "v"(s1))
#define PKMUL(d,a,b)       asm("v_pk_mul_f32 %0, %1, %2" : "=v"(d) : "v"(a), "v"(b))

__device__ __forceinline__ uint32_t rotl32(uint32_t v, int n) {
  return __builtin_amdgcn_alignbit(v, v, (uint32_t)(32 - n));
}

// Threefry-2x32, 20 rounds — matches jax/_src/prng.py exactly.
__device__ __forceinline__ void tf2x32(uint32_t k0, uint32_t k1,
                                       uint32_t& x0, uint32_t& x1) {
  uint32_t k2 = k0 ^ k1 ^ 0x1BD11BDAu;
  x0 += k0; x1 += k1;
#define TFR(r) { x0 += x1; x1 = rotl32(x1,(r)); x1 ^= x0; }
  TFR(13) TFR(15) TFR(26) TFR(6)
  x0 += k1; x1 += k2 + 1u;
  TFR(17) TFR(29) TFR(16) TFR(24)
  x0 += k2; x1 += k0 + 2u;
  TFR(13) TFR(15) TFR(26) TFR(6)
  x0 += k0; x1 += k1 + 3u;
  TFR(17) TFR(29) TFR(16) TFR(24)
  x0 += k1; x1 += k2 + 4u;
  TFR(13) TFR(15) TFR(26) TFR(6)
  x0 += k2; x1 += k0 + 5u;
#undef TFR
}

__device__ __forceinline__ uint32_t tf_bits(uint32_t k0, uint32_t k1, uint32_t n) {
  uint32_t x0 = 0u, x1 = n;
  tf2x32(k0, k1, x0, x1);
  return x0 ^ x1;
}

// two bit-draws -> two sqrt(2)*erfinv(uniform) normals; XLA ErfInv32 constants.
__device__ __forceinline__ v2f b2n_pk(uint32_t b0, uint32_t b1) {
  const float MN = -0.99999994039535522461f;   // nextafterf(-1,0)
  v2f f = { __uint_as_float((b0 >> 9) | 0x3F800000u),
            __uint_as_float((b1 >> 9) | 0x3F800000u) };
  v2f fm = f - 1.0f;                            // [0,1)
  v2f u = __builtin_elementwise_fma(fm, (v2f)2.0f, (v2f)MN);
  u = __builtin_elementwise_max(u, (v2f)MN);
  v2f x2 = u * u;
  v2f om = 1.0f - x2;
  v2f w  = { -__logf(om.x), -__logf(om.y) };
  v2f ws = w - 2.5f;
  v2f ps = (v2f)2.81022636e-08f;
  ps = __builtin_elementwise_fma(ps, ws, (v2f)3.43273939e-07f);
  ps = __builtin_elementwise_fma(ps, ws, (v2f)-3.5233877e-06f);
  ps = __builtin_elementwise_fma(ps, ws, (v2f)-4.39150654e-06f);
  ps = __builtin_elementwise_fma(ps, ws, (v2f)0.00021858087f);
  ps = __builtin_elementwise_fma(ps, ws, (v2f)-0.00125372503f);
  ps = __builtin_elementwise_fma(ps, ws, (v2f)-0.00417768164f);
  ps = __builtin_elementwise_fma(ps, ws, (v2f)0.246640727f);
  ps = __builtin_elementwise_fma(ps, ws, (v2f)1.50140941f);
  v2f p = ps;
  const int big = (w.x >= 5.0f) | (w.y >= 5.0f);
  if (__any(big)) {                       // rare tail (|u| > 0.9966)
    v2f sq = { sqrtf(w.x), sqrtf(w.y) };
    v2f wb = sq - 3.0f;
    v2f pb = (v2f)-0.000200214257f;
    pb = __builtin_elementwise_fma(pb, wb, (v2f)0.000100950558f);
    pb = __builtin_elementwise_fma(pb, wb, (v2f)0.00134934322f);
    pb = __builtin_elementwise_fma(pb, wb, (v2f)-0.00367342844f);
    pb = __builtin_elementwise_fma(pb, wb, (v2f)0.00573950773f);
    pb = __builtin_elementwise_fma(pb, wb, (v2f)-0.0076224613f);
    pb = __builtin_elementwise_fma(pb, wb, (v2f)0.00943887047f);
    pb = __builtin_elementwise_fma(pb, wb, (v2f)1.00167406f);
    pb = __builtin_elementwise_fma(pb, wb, (v2f)2.83297682f);
    p.x = (w.x < 5.0f) ? ps.x : pb.x;
    p.y = (w.y < 5.0f) ? ps.y : pb.y;
  }
  return (p * u) * 1.41421356237309515f;
}

__global__ __launch_bounds__(THREADS)
void gdiff_kernel(const float* __restrict__ x,
                  const float* __restrict__ alpha, const float* __restrict__ sigma,
                  const float* __restrict__ ew1, const float* __restrict__ eb1,
                  const float* __restrict__ ew2, const float* __restrict__ eb2,
                  const float* __restrict__ gw1, const float* __restrict__ gb1,
                  const float* __restrict__ gw2, const float* __restrict__ gb2,
                  const float* __restrict__ gw3, const float* __restrict__ gb3,
                  float* __restrict__ out)
{
  extern __shared__ float sm[];
  const int t    = threadIdx.x;
  const int pr   = t >> 5;                  // row-pair 0..31
  const int c    = t & 31;
  const int half = c >> 4;                  // which row of the pair
  const int cf   = c & 15;                  // lane-in-row 0..15
  const int q    = cf & 7;                  // f/g quad index
  const int dh   = cf >> 3;                 // d-half / f-half for L1/L2 split
  const int rid  = pr + (half << 5);        // LDS row 0..63
  const int zrow = rid * ZSTR + (half << 3);// +8 float shift decorrelates halves
  const uint32_t rowg = (uint32_t)(blockIdx.x * 32 + pr + half * HALFB);
  const uint32_t nb   = rowg * 256u + (uint32_t)cf;

  v4f hq0, hq1, hq2, hq3, hq4, hq5, hq6, hq7;  // 32 broadcast h values

  // ---------- staging helpers ----------
  auto stage_w1 = [&](const float* __restrict__ w) {   // [256][32]
    const int r = t >> 2, part = t & 3;
#pragma unroll
    for (int s = 0; s < 2; ++s)
      *(v4f*)&sm[W1_OFF + r * 32 + part * 8 + 4 * s] =
          *(const v4f*)&w[r * 32 + part * 8 + 4 * s];
  };
  auto stage_w3t = [&](const float* __restrict__ w) {  // [32][256] -> [d][g]
    const int g = t >> 5, dc = t & 31;
#pragma unroll
    for (int s = 0; s < 2; ++s) {
      const int d0 = dc * 8 + s * 4;
      v4f v = *(const v4f*)&w[g * 256 + d0];
      sm[W3_OFF + (d0 + 0) * WS + g] = v.x;
      sm[W3_OFF + (d0 + 1) * WS + g] = v.y;
      sm[W3_OFF + (d0 + 2) * WS + g] = v.z;
      sm[W3_OFF + (d0 + 3) * WS + g] = v.w;
    }
  };

  // ---------- layer 1: d-half-split partials ----------
  auto layer1 = [&](v2f& h01, v2f& h23) {
    v4f bv = { 0.f, 0.f, 0.f, 0.f };
    if (!dh) bv = *(const v4f*)&sm[B1_OFF + 4 * q];
    h01 = bv.xy; h23 = bv.zw;
    const float* zr_ = &sm[zrow + (dh << 7)];
    const float* wp  = &sm[W1_OFF + (dh << 12) + 4 * q];
#pragma unroll 4
    for (int d0 = 0; d0 < 128; d0 += 4) {
      v4f z4 = *(const v4f*)&zr_[d0];
      v4f wa = *(const v4f*)&wp[(d0 + 0) * 32];
      v4f wb = *(const v4f*)&wp[(d0 + 1) * 32];
      v4f wc = *(const v4f*)&wp[(d0 + 2) * 32];
      v4f wd = *(const v4f*)&wp[(d0 + 3) * 32];
      PKFMA_L(h01, z4.xy, wa.xy); PKFMA_L(h23, z4.xy, wa.zw);
      PKFMA_H(h01, z4.xy, wb.xy); PKFMA_H(h23, z4.xy, wb.zw);
      PKFMA_L(h01, z4.zw, wc.xy); PKFMA_L(h23, z4.zw, wc.zw);
      PKFMA_H(h01, z4.zw, wd.xy); PKFMA_H(h23, z4.zw, wd.zw);
    }
  };
  auto red8_relu = [&](v2f& a, v2f& b) {     // cross-half reduce + relu
    a.x += __shfl_xor(a.x, 8); a.y += __shfl_xor(a.y, 8);
    b.x += __shfl_xor(b.x, 8); b.y += __shfl_xor(b.y, 8);
    a = __builtin_elementwise_max(a, (v2f)0.f);
    b = __builtin_elementwise_max(b, (v2f)0.f);
  };
  auto hwrite = [&](v2f a, v2f b) {
    if (!dh) { v4f hv; hv.xy = a; hv.zw = b;
               *(v4f*)&sm[HB_OFF + rid * WS + 4 * q] = hv; }
  };
  auto hload8 = [&]() {
    const float* hb = &sm[HB_OFF + rid * WS];
    hq0 = *(const v4f*)&hb[0];  hq1 = *(const v4f*)&hb[4];
    hq2 = *(const v4f*)&hb[8];  hq3 = *(const v4f*)&hb[12];
    hq4 = *(const v4f*)&hb[16]; hq5 = *(const v4f*)&hb[20];
    hq6 = *(const v4f*)&hb[24]; hq7 = *(const v4f*)&hb[28];
  };
  // ---------- layer 2: f-half-split partials ----------
  auto layer2 = [&](v2f& g01, v2f& g23) {
    const float* hb = &sm[HB_OFF + rid * WS + (dh << 4)];
    v4f hA = *(const v4f*)&hb[0], hB = *(const v4f*)&hb[4];
    v4f hC = *(const v4f*)&hb[8], hD = *(const v4f*)&hb[12];
    v4f bv = { 0.f, 0.f, 0.f, 0.f };
    if (!dh) bv = *(const v4f*)&sm[B2_OFF + 4 * q];
    g01 = bv.xy; g23 = bv.zw;
    const float* w2c = &sm[W2_OFF + (dh << 4) * WS + 4 * q];
#define L2M(hqm, mm) { \
    v4f wA = *(const v4f*)&w2c[(4*(mm)+0)*WS]; \
    v4f wB = *(const v4f*)&w2c[(4*(mm)+1)*WS]; \
    v4f wC = *(const v4f*)&w2c[(4*(mm)+2)*WS]; \
    v4f wD = *(const v4f*)&w2c[(4*(mm)+3)*WS]; \
    PKFMA_L(g01, hqm.xy, wA.xy); PKFMA_L(g23, hqm.xy, wA.zw); \
    PKFMA_H(g01, hqm.xy, wB.xy); PKFMA_H(g23, hqm.xy, wB.zw); \
    PKFMA_L(g01, hqm.zw, wC.xy); PKFMA_L(g23, hqm.zw, wC.zw); \
    PKFMA_H(g01, hqm.zw, wD.xy); PKFMA_H(g23, hqm.zw, wD.zw); }
    L2M(hA,0) L2M(hB,1) L2M(hC,2) L2M(hD,3)
#undef L2M
  };
  // ---------- layer 3 (or encoder L2) + fused diffuse; z -> LDS ----------
  auto l3d = [&](uint32_t e0, uint32_t e1, const float* ae, const float* se,
                 bool relu) {
#pragma unroll
    for (int kp = 0; kp < 8; ++kp) {
      const int dlo = cf + 32 * kp;
      const int dhi = dlo + 16;
      v2f acc0 = { sm[B3_OFF + dlo], 0.f };
      v2f acc1 = { sm[B3_OFF + dhi], 0.f };
      const float* wl = &sm[W3_OFF + dlo * WS];
      const float* wh = &sm[W3_OFF + dhi * WS];
#define L3M(hqm, off) { \
      v4f wvl = *(const v4f*)&wl[off]; \
      v4f wvh = *(const v4f*)&wh[off]; \
      PKFMA(acc0, hqm.xy, wvl.xy); PKFMA(acc0, hqm.zw, wvl.zw); \
      PKFMA(acc1, hqm.xy, wvh.xy); PKFMA(acc1, hqm.zw, wvh.zw); }
      L3M(hq0, 0)  L3M(hq1, 4)  L3M(hq2, 8)  L3M(hq3, 12)
      L3M(hq4, 16) L3M(hq5, 20) L3M(hq6, 24) L3M(hq7, 28)
#undef L3M
      float z0 = acc0.x + acc0.y;
      float z1 = acc1.x + acc1.y;
      if (relu) { z0 = fmaxf(z0, 0.f); z1 = fmaxf(z1, 0.f); }
      const uint32_t n0 = nb + (uint32_t)(32 * kp);
      v2f nrm = b2n_pk(tf_bits(e0, e1, n0), tf_bits(e0, e1, n0 + 16u));
      v2f a2 = { ae[dlo], ae[dhi] };
      v2f s2 = { se[dlo], se[dhi] };
      v2f z2 = { z0, z1 };
      v2f zd; PKMUL(zd, z2, a2); PKFMA(zd, s2, nrm);
      sm[zrow + dlo] = zd.x;
      sm[zrow + dhi] = zd.y;
    }
  };

  // ---------------- stage x + encoder weights + tables ----------------
  {
    const int zr = t >> 4, jj = t & 15;
    const int gr = (zr < 32) ? (blockIdx.x * 32 + zr)
                             : (blockIdx.x * 32 + zr - 32 + HALFB);
    const v4f* src = (const v4f*)(x + (size_t)gr * 256 + jj * 16);
    const int zb = zr * ZSTR + ((zr >> 5) << 3);
#pragma unroll
    for (int s = 0; s < 4; ++s)
      *(v4f*)&sm[zb + jj * 16 + 4 * s] = src[s];
  }
  stage_w1(ew1);
  stage_w3t(ew2);
  if (t < 256) {
    const float al = alpha[t];
    sm[AL_OFF + t] = al;
    sm[AE_OFF + 256 + t] = __expf(-0.5f * al * 0.99f);   // a-table for j=99 (buf 1)
    sm[B3_OFF + t] = eb2[t];
    if (t < 32) sm[B1_OFF + t] = eb1[t];
  } else if (t < 512) {
    const int d = t - 256;
    const float sg = sigma[d];
    sm[SG_OFF + d] = sg;
    sm[SE_OFF + 256 + d] = __expf(0.5f * sg * 0.99f);    // s-table for j=99 (buf 1)
  }
  __syncthreads();

  // ---------------- encoder: L1(+relu) -> L2(no relu) + diffuse(99) ----------------
  {
    v2f h01, h23;
    layer1(h01, h23);
    red8_relu(h01, h23);
    hwrite(h01, h23);
    hload8();
    uint32_t e0 = 0u, e1 = 99u;
    tf2x32(0u, 42u, e0, e1);
    l3d(e0, e1, &sm[AE_OFF + 256], &sm[SE_OFF + 256], false);
  }
  __syncthreads();

  // ---------------- restage generator weights ----------------
  stage_w1(gw1);
  stage_w3t(gw3);
  if (t < 256) {
    sm[B3_OFF + t] = gb3[t];
    if (t < 32) { sm[B1_OFF + t] = gb1[t]; sm[B2_OFF + t] = gb2[t]; }
    const int r = t >> 3, s8 = t & 7;   // gw2 [32][32] -> [32][36]
    *(v4f*)&sm[W2_OFF + r * WS + 4 * s8] = *(const v4f*)&gw2[r * 32 + 4 * s8];
  }
  __syncthreads();

  // ---------------- 99 iterations: 1 barrier/step (a/s table dbuf) ----------------
#pragma unroll 1
  for (int i = 99; i >= 1; --i) {
    const int j = i - 1;
    const float tt = (float)j * 0.01f;
    const int buf = (j & 1) << 8;
    if (t < 256)      sm[AE_OFF + buf + t]       = __expf(-0.5f * sm[AL_OFF + t] * tt);
    else if (t < 512) sm[SE_OFF + buf + (t-256)] = __expf( 0.5f * sm[SG_OFF + (t-256)] * tt);
    __syncthreads();   // table(j) ready; also fences z hand-off parity

    v2f h01, h23;
    layer1(h01, h23);
    red8_relu(h01, h23);
    hwrite(h01, h23);

    v2f g01, g23;
    layer2(g01, g23);
    red8_relu(g01, g23);
    hwrite(g01, g23);
    hload8();

    uint32_t e0 = 0u, e1 = (uint32_t)j;
    tf2x32(0u, 42u, e0, e1);
    l3d(e0, e1, &sm[AE_OFF + buf], &sm[SE_OFF + buf], true);
  }
  __syncthreads();

  // ---------------- coalesced output copy ----------------
  {
    const int zr = t >> 4, jj = t & 15;
    const int gr = (zr < 32) ? (blockIdx.x * 32 + zr)
                             : (blockIdx.x * 32 + zr - 32 + HALFB);
    v4f* dst = (v4f*)(out + (size_t)gr * 256 + jj * 16);
    const int zb = zr * ZSTR + ((zr >> 5) << 3);
#pragma unroll
    for (int s = 0; s < 4; ++s)
      dst[s] = *(const v4f*)&sm[zb + jj * 16 + 4 * s];
  }
}

extern "C" void kernel_launch(void* const* d_in, const int* in_sizes, int n_in,
                              void* d_out, int out_size, void* d_ws, size_t ws_size,
                              hipStream_t stream) {
  (void)in_sizes; (void)n_in; (void)d_ws; (void)ws_size; (void)out_size;
  const float* x     = (const float*)d_in[0];
  const float* alpha = (const float*)d_in[1];
  const float* sigma = (const float*)d_in[2];
  const float* ew1   = (const float*)d_in[3];
  const float* eb1   = (const float*)d_in[4];
  const float* ew2   = (const float*)d_in[5];
  const float* eb2   = (const float*)d_in[6];
  const float* gw1   = (const float*)d_in[7];
  const float* gb1   = (const float*)d_in[8];
  const float* gw2   = (const float*)d_in[9];
  const float* gb2   = (const float*)d_in[10];
  const float* gw3   = (const float*)d_in[11];
  const float* gb3   = (const float*)d_in[12];
  float* out = (float*)d_out;

  (void)hipFuncSetAttribute((const void*)gdiff_kernel,
                            hipFuncAttributeMaxDynamicSharedMemorySize, LDS_BYTES);

  gdiff_kernel<<<256, THREADS, LDS_BYTES, stream>>>(
      x, alpha, sigma, ew1, eb1, ew2, eb2, gw1, gb1, gw2, gb2, gw3, gb3, out);
}